// Round 7
// baseline (320.568 us; speedup 1.0000x reference)
//
#include <hip/hip_runtime.h>
#include <math.h>
#include <float.h>

#define HW 4096
#define CHW 262144
#define NTOK 65536
#define NELEM 4194304

// ws float offsets
#define WS_LOSS 0        // 512 floats
#define WS_STD  512      // 64
#define WS_EE   576      // 1024 (exact fp32 row norms)
#define WS_E2   1600     // 65536 ushorts (codebook bf16 hi|lo, [k][128])

#define EPSM 2.0e-3f     // ambiguity margin (>=13x the rigorous error bound)

typedef __attribute__((ext_vector_type(8))) short bf16x8;
typedef __attribute__((ext_vector_type(4))) float f32x4;

__device__ __forceinline__ unsigned short f2bf(float x) {
  unsigned u = __float_as_uint(x);
  u += 0x7FFFu + ((u >> 16) & 1u);
  return (unsigned short)(u >> 16);
}
__device__ __forceinline__ float bf2f(unsigned short h) {
  return __uint_as_float(((unsigned)h) << 16);
}

// ---------------- k_pre: blocks 0..63 std, 64..79 codebook decompose ----------------
__global__ __launch_bounds__(1024) void k_pre(const float* __restrict__ z,
                                              const float* __restrict__ emb,
                                              float* __restrict__ stdv,
                                              unsigned short* __restrict__ e2g,
                                              float* __restrict__ eeg) {
  __shared__ double rs[16], rs2[16];
  int tid = threadIdx.x;
  int blk = blockIdx.x;
  if (blk < 64) {
    // per-channel std (ddof=1) — bit-identical to validated rounds
    int c = blk;
    double s = 0.0, s2 = 0.0;
    const float* base = z + c * HW;
    #pragma unroll 4
    for (int jj = 0; jj < 16; ++jj) {
      int f = tid + (jj << 10);
      int b = f >> 10, off4 = f & 1023;
      float4 v = *(const float4*)(base + (size_t)b * CHW + (off4 << 2));
      s  += (double)v.x + (double)v.y + (double)v.z + (double)v.w;
      s2 += (double)v.x * v.x + (double)v.y * v.y + (double)v.z * v.z + (double)v.w * v.w;
    }
    for (int o = 32; o > 0; o >>= 1) {
      s += __shfl_down(s, o, 64);
      s2 += __shfl_down(s2, o, 64);
    }
    int wv = tid >> 6, ln = tid & 63;
    if (ln == 0) { rs[wv] = s; rs2[wv] = s2; }
    __syncthreads();
    if (tid == 0) {
      double S = 0.0, S2 = 0.0;
      #pragma unroll
      for (int w = 0; w < 16; ++w) { S += rs[w]; S2 += rs2[w]; }
      const double N = (double)NTOK;
      double var = (S2 - S * S / N) / (N - 1.0);
      float sd = (float)sqrt(var);
      stdv[c] = fmaxf(sd, 1e-5f);
    }
  } else {
    // 64 codes: exact norms (sequential fmaf) + bf16 hi|lo decomposition
    int k0 = (blk - 64) << 6;
    {
      int code = tid >> 4, c4 = tid & 15;
      float4 v = *(const float4*)(emb + (size_t)((k0 + code) << 6) + (c4 << 2));
      unsigned short h0 = f2bf(v.x), h1 = f2bf(v.y), h2 = f2bf(v.z), h3 = f2bf(v.w);
      unsigned short l0 = f2bf(v.x - bf2f(h0)), l1 = f2bf(v.y - bf2f(h1));
      unsigned short l2 = f2bf(v.z - bf2f(h2)), l3 = f2bf(v.w - bf2f(h3));
      unsigned short* row = e2g + (size_t)(k0 + code) * 128;
      *(uint2*)(row + (c4 << 2)) =
          make_uint2((unsigned)h0 | ((unsigned)h1 << 16), (unsigned)h2 | ((unsigned)h3 << 16));
      *(uint2*)(row + 64 + (c4 << 2)) =
          make_uint2((unsigned)l0 | ((unsigned)l1 << 16), (unsigned)l2 | ((unsigned)l3 << 16));
    }
    if (tid < 64) {
      const float* er = emb + (size_t)((k0 + tid) << 6);
      float s = 0.f;
      #pragma unroll
      for (int c = 0; c < 64; ++c) s = fmaf(er[c], er[c], s);
      eeg[k0 + tid] = s;
    }
  }
}

// ---------------- main kernel: MFMA phase-1 argmin + exact fixup + epilogue ----------------
__global__ __launch_bounds__(256, 2) void k_vq(
    const float* __restrict__ z_e, const float* __restrict__ emb,
    const float* __restrict__ stdv, const float* __restrict__ eeg,
    const unsigned short* __restrict__ e2g,
    float* __restrict__ out_zq, float* __restrict__ out_idx,
    float* __restrict__ loss_part) {
  __shared__ unsigned short Abuf[128 * 136];  // z2 [tok][c2], pad 8 -> 2-way only
  __shared__ unsigned short Bt[128 * 136];    // code tile [code][c2]
  __shared__ float eeS[1024];
  __shared__ float sstd[64];
  __shared__ float mbd[2][128];
  __shared__ float msec[2][128];
  __shared__ int   mbk[2][128];
  __shared__ int   skf[128];
  __shared__ int   ambList[128];
  __shared__ int   ambN;
  __shared__ float sred[4];

  int tid = threadIdx.x;
  int lane = tid & 63;
  int wv = tid >> 6;
  int blk = blockIdx.x;
  int b = blk >> 5;
  int s0 = (blk & 31) << 7;

  if (tid < 64) sstd[tid] = stdv[tid];
  #pragma unroll
  for (int j = 0; j < 4; ++j) eeS[tid + (j << 8)] = eeg[tid + (j << 8)];
  if (tid == 0) ambN = 0;
  __syncthreads();

  // ---- stage A: normalize (IEEE div, bit-exact path) + bf16 hi/lo decompose ----
  {
    int tok = tid & 127, sect = tid >> 7;
    const float* zsrc = z_e + (size_t)b * CHW + (size_t)(sect << 5) * HW + s0 + tok;
    unsigned hw[16], lw[16];
    #pragma unroll
    for (int cc = 0; cc < 32; ++cc) {
      float v = zsrc[(size_t)cc * HW] / sstd[(sect << 5) + cc];
      unsigned short h = f2bf(v);
      unsigned short l = f2bf(v - bf2f(h));
      if (cc & 1) { hw[cc >> 1] |= ((unsigned)h) << 16; lw[cc >> 1] |= ((unsigned)l) << 16; }
      else        { hw[cc >> 1] = h;                    lw[cc >> 1] = l; }
    }
    unsigned short* arow = Abuf + tok * 136;
    #pragma unroll
    for (int q = 0; q < 4; ++q) {
      *(uint4*)(arow + (sect << 5) + (q << 3)) =
          make_uint4(hw[4 * q], hw[4 * q + 1], hw[4 * q + 2], hw[4 * q + 3]);
      *(uint4*)(arow + 64 + (sect << 5) + (q << 3)) =
          make_uint4(lw[4 * q], lw[4 * q + 1], lw[4 * q + 2], lw[4 * q + 3]);
    }
  }

  int quad = lane >> 4, l15 = lane & 15;
  int wt = wv >> 1, wc = wv & 1;

  float bd[16], sec[16];
  int bk[16];
  #pragma unroll
  for (int i = 0; i < 16; ++i) { bd[i] = FLT_MAX; sec[i] = FLT_MAX; bk[i] = 0; }

  for (int ct = 0; ct < 8; ++ct) {
    __syncthreads();   // A ready (first iter) / previous tile's frags consumed
    {  // stage B tile (32 KB) from precomputed e2g
      int code = tid >> 1, part = tid & 1;
      const uint4* src = (const uint4*)(e2g + ((size_t)((ct << 7) + code) << 7) + (part << 6));
      uint4* dst = (uint4*)(Bt + code * 136 + (part << 6));
      #pragma unroll
      for (int j = 0; j < 8; ++j) dst[j] = src[j];
    }
    __syncthreads();

    f32x4 acc[4][4];
    #pragma unroll
    for (int mt = 0; mt < 4; ++mt)
      #pragma unroll
      for (int nt = 0; nt < 4; ++nt) acc[mt][nt] = (f32x4)(0.f);

    // dot2 = zh*eh + zl*eh + zh*el  (K'=192 over hi/lo slabs)
    const int aoffs[6] = {0, 32, 64, 96, 0, 32};
    const int boffs[6] = {0, 32, 0, 32, 64, 96};
    #pragma unroll
    for (int s = 0; s < 6; ++s) {
      bf16x8 af[4], bfr[4];
      #pragma unroll
      for (int mt = 0; mt < 4; ++mt)
        af[mt] = *(const bf16x8*)(Abuf + ((wt << 6) + (mt << 4) + l15) * 136 + aoffs[s] + (quad << 3));
      #pragma unroll
      for (int nt = 0; nt < 4; ++nt)
        bfr[nt] = *(const bf16x8*)(Bt + ((wc << 6) + (nt << 4) + l15) * 136 + boffs[s] + (quad << 3));
      #pragma unroll
      for (int mt = 0; mt < 4; ++mt)
        #pragma unroll
        for (int nt = 0; nt < 4; ++nt)
          acc[mt][nt] = __builtin_amdgcn_mfma_f32_16x16x32_bf16(af[mt], bfr[nt], acc[mt][nt], 0, 0, 0);
    }

    // eval: s = ee - 2*dot2 ; track top-2 per row-slot (k ascending across ct)
    int kbase = (ct << 7) + (wc << 6);
    #pragma unroll
    for (int nt = 0; nt < 4; ++nt) {
      int kcode = kbase + (nt << 4) + l15;
      float eev = eeS[kcode];
      #pragma unroll
      for (int mt = 0; mt < 4; ++mt) {
        #pragma unroll
        for (int r = 0; r < 4; ++r) {
          float sv = fmaf(-2.0f, acc[mt][nt][r], eev);
          int slot = (mt << 2) + r;
          if (sv < bd[slot]) { sec[slot] = bd[slot]; bd[slot] = sv; bk[slot] = kcode; }
          else if (sv < sec[slot]) { sec[slot] = sv; }
        }
      }
    }
  }

  // top-2 merge across the 16 cols (lane&15), tie -> smaller k
  #pragma unroll
  for (int m = 1; m <= 8; m <<= 1) {
    #pragma unroll
    for (int slot = 0; slot < 16; ++slot) {
      float obd = __shfl_xor(bd[slot], m, 64);
      int   obk = __shfl_xor(bk[slot], m, 64);
      float osec = __shfl_xor(sec[slot], m, 64);
      if (obd < bd[slot] || (obd == bd[slot] && obk < bk[slot])) {
        sec[slot] = fminf(bd[slot], osec); bd[slot] = obd; bk[slot] = obk;
      } else {
        sec[slot] = fminf(sec[slot], obd);
      }
    }
  }
  if (l15 == 0) {
    #pragma unroll
    for (int mt = 0; mt < 4; ++mt)
      #pragma unroll
      for (int r = 0; r < 4; ++r) {
        int t = (wt << 6) + (mt << 4) + (quad << 2) + r;
        int slot = (mt << 2) + r;
        mbd[wc][t] = bd[slot]; mbk[wc][t] = bk[slot]; msec[wc][t] = sec[slot];
      }
  }
  __syncthreads();

  // merge code halves; flag ambiguous tokens for exact fixup
  if (tid < 128) {
    float b0 = mbd[0][tid], b1 = mbd[1][tid];
    int k0 = mbk[0][tid], k1 = mbk[1][tid];
    float fbd, fsec; int fbk;
    if (b1 < b0 || (b1 == b0 && k1 < k0)) { fbd = b1; fbk = k1; fsec = fminf(b0, msec[1][tid]); }
    else                                  { fbd = b0; fbk = k0; fsec = fminf(msec[0][tid], b1); }
    skf[tid] = fbk;
    if (fsec - fbd <= EPSM) { int p = atomicAdd(&ambN, 1); ambList[p] = tid; }
  }
  __syncthreads();

  // ---- exact fixup (rare): full scan with the bit-exact reference formula ----
  {
    int na = ambN;
    for (int i = wv; i < na; i += 4) {
      int t = ambList[i];
      float zvl = z_e[(size_t)b * CHW + (size_t)lane * HW + s0 + t] / sstd[lane];
      float zz = 0.f;
      #pragma unroll
      for (int c = 0; c < 64; ++c) { float zc = __shfl(zvl, c, 64); zz = fmaf(zc, zc, zz); }
      float bdl = FLT_MAX; int bkl = 0;
      for (int kk = 0; kk < 16; ++kk) {
        int k = (lane << 4) + kk;              // ascending within lane chunk
        const float* er = emb + ((size_t)k << 6);
        float dot = 0.f;
        #pragma unroll
        for (int c4 = 0; c4 < 16; ++c4) {
          float4 ev = *(const float4*)(er + (c4 << 2));
          dot = fmaf(ev.x, __shfl(zvl, (c4 << 2) + 0, 64), dot);
          dot = fmaf(ev.y, __shfl(zvl, (c4 << 2) + 1, 64), dot);
          dot = fmaf(ev.z, __shfl(zvl, (c4 << 2) + 2, 64), dot);
          dot = fmaf(ev.w, __shfl(zvl, (c4 << 2) + 3, 64), dot);
        }
        float dd = (zz - 2.0f * dot) + eeS[k];
        if (dd < bdl) { bdl = dd; bkl = k; }
      }
      #pragma unroll
      for (int m = 1; m <= 32; m <<= 1) {
        float od = __shfl_xor(bdl, m, 64);
        int   ok = __shfl_xor(bkl, m, 64);
        if (od < bdl || (od == bdl && ok < bkl)) { bdl = od; bkl = ok; }
      }
      if (lane == 0) skf[t] = bkl;
    }
  }
  __syncthreads();

  if (tid < 128) out_idx[(blk << 7) + tid] = (float)skf[tid];

  // ---- epilogue: z recomputed bit-exactly from global, coalesced stores ----
  {
    int t = tid & 127;
    int ch = tid >> 7;
    int kq = skf[t];
    const float* eq = emb + ((size_t)kq << 6) + (ch << 5);
    const float* zb2 = z_e + (size_t)b * CHW + s0 + t;
    float* ob = out_zq + (size_t)b * CHW + s0 + t;
    float lsum = 0.f;
    #pragma unroll
    for (int jj = 0; jj < 32; ++jj) {
      int c = (ch << 5) + jj;
      float zv = zb2[(size_t)c * HW] / sstd[c];
      float e = eq[jj];
      float df = zv - e;
      lsum = fmaf(df, df, lsum);
      ob[(size_t)c * HW] = zv + (e - zv);
    }
    for (int o = 32; o > 0; o >>= 1) lsum += __shfl_down(lsum, o, 64);
    if (lane == 0) sred[wv] = lsum;
  }
  __syncthreads();
  if (tid == 0) loss_part[blk] = sred[0] + sred[1] + sred[2] + sred[3];
}

// ---------------- k_post: histogram + vq_loss + perplexity (validated r5) ----------------
__global__ __launch_bounds__(1024) void k_post(const float* __restrict__ loss_part,
                                               const float* __restrict__ out_idx,
                                               float* __restrict__ out_scalars) {
  __shared__ int hist[1024];
  __shared__ double rl[16], rh[16];
  int tid = threadIdx.x;
  hist[tid] = 0;
  __syncthreads();
  const float2* idx2 = (const float2*)out_idx;
  #pragma unroll
  for (int jj = 0; jj < 32; ++jj) {
    float2 v = idx2[tid + (jj << 10)];
    atomicAdd(&hist[(int)v.x], 1);
    atomicAdd(&hist[(int)v.y], 1);
  }
  __syncthreads();
  double ls = 0.0;
  if (tid < 512) ls = (double)loss_part[tid];
  float p = (float)hist[tid] * (1.0f / 65536.0f);
  float lg = logf(fmaxf(p, 1e-10f));
  double hs = (double)(p * lg);
  for (int o = 32; o > 0; o >>= 1) {
    ls += __shfl_down(ls, o, 64);
    hs += __shfl_down(hs, o, 64);
  }
  int wv = tid >> 6, ln = tid & 63;
  if (ln == 0) { rl[wv] = ls; rh[wv] = hs; }
  __syncthreads();
  if (tid == 0) {
    double L = 0.0, Hn = 0.0;
    #pragma unroll
    for (int w = 0; w < 16; ++w) { L += rl[w]; Hn += rh[w]; }
    float m = (float)(L / (double)NELEM);
    out_scalars[0] = 0.25f * m + m;
    out_scalars[1] = expf((float)(-Hn));
  }
}

extern "C" void kernel_launch(void* const* d_in, const int* in_sizes, int n_in,
                              void* d_out, int out_size, void* d_ws, size_t ws_size,
                              hipStream_t stream) {
  const float* z_e = (const float*)d_in[0];
  const float* emb = (const float*)d_in[1];
  float* ws = (float*)d_ws;
  float* loss_part = ws + WS_LOSS;
  float* stdv = ws + WS_STD;
  float* eeg = ws + WS_EE;
  unsigned short* e2g = (unsigned short*)(ws + WS_E2);   // ws use ~137 KB

  float* out = (float*)d_out;
  float* out_zq = out;                  // 4194304
  float* out_scalars = out + NELEM;     // vq_loss, perplexity
  float* out_idx = out + NELEM + 2;     // 65536 indices as float

  k_pre<<<80, 1024, 0, stream>>>(z_e, emb, stdv, e2g, eeg);
  k_vq<<<512, 256, 0, stream>>>(z_e, emb, stdv, eeg, e2g, out_zq, out_idx, loss_part);
  k_post<<<1, 1024, 0, stream>>>(loss_part, out_idx, out_scalars);
}